// Round 1
// baseline (388.355 us; speedup 1.0000x reference)
//
#include <hip/hip_runtime.h>
#include <hip/hip_bf16.h>
#include <math.h>

// Problem constants (B=2,S=2048 -> T=4096 tokens)
#define T_TOKENS 4096
#define D_DIM 768
#define F_DIM 3072
#define E_NUM 8

#define BM 128
#define BN 128
#define BK 32

typedef __attribute__((ext_vector_type(8))) short short8;
typedef __attribute__((ext_vector_type(4))) float float4v;
typedef unsigned short ushort_t;

__device__ __forceinline__ ushort_t f2bf(float f) {
    union { float f; unsigned u; } v; v.f = f;
    unsigned r = v.u + 0x7fffu + ((v.u >> 16) & 1u);   // RNE
    return (ushort_t)(r >> 16);
}

#define GLOAD_LDS16(gp, lp) __builtin_amdgcn_global_load_lds( \
    (const __attribute__((address_space(1))) void*)(gp),      \
    (__attribute__((address_space(3))) void*)(lp), 16, 0, 0)

// ---------------------------------------------------------------- init
__global__ void k_init(float* __restrict__ out, int* __restrict__ counts) {
    int i = blockIdx.x * 256 + threadIdx.x;
    if (blockIdx.x == 0 && threadIdx.x < E_NUM) counts[threadIdx.x] = 0;
    for (int j = i; j < T_TOKENS * D_DIM; j += gridDim.x * 256) out[j] = 0.f;
}

// ---------------------------------------------------------------- gate
// fp32 logits + softmax + top-2 (first-index tie-break, matches lax.top_k)
__global__ void k_gate(const float* __restrict__ x, const float* __restrict__ gw,
                       int* __restrict__ counts, int* __restrict__ list,
                       float* __restrict__ wtmp) {
    int wave = threadIdx.x >> 6;
    int lane = threadIdx.x & 63;
    int t = blockIdx.x * 4 + wave;
    if (t >= T_TOKENS) return;
    float acc[E_NUM];
#pragma unroll
    for (int e = 0; e < E_NUM; ++e) acc[e] = 0.f;
    const float* xr = x + (size_t)t * D_DIM;
    for (int d = lane; d < D_DIM; d += 64) {
        float xv = xr[d];
        const float* g = gw + d * E_NUM;
#pragma unroll
        for (int e = 0; e < E_NUM; ++e) acc[e] += xv * g[e];
    }
#pragma unroll
    for (int e = 0; e < E_NUM; ++e) {
#pragma unroll
        for (int s = 32; s >= 1; s >>= 1) acc[e] += __shfl_xor(acc[e], s);
    }
    if (lane == 0) {
        float mx = acc[0];
#pragma unroll
        for (int e = 1; e < E_NUM; ++e) mx = fmaxf(mx, acc[e]);
        float p[E_NUM], sum = 0.f;
#pragma unroll
        for (int e = 0; e < E_NUM; ++e) { p[e] = expf(acc[e] - mx); sum += p[e]; }
        float inv = 1.f / sum;
#pragma unroll
        for (int e = 0; e < E_NUM; ++e) p[e] *= inv;
        int e1 = 0;
#pragma unroll
        for (int e = 1; e < E_NUM; ++e) if (p[e] > p[e1]) e1 = e;
        int e2 = (e1 == 0) ? 1 : 0;
#pragma unroll
        for (int e = 0; e < E_NUM; ++e) if (e != e1 && p[e] > p[e2]) e2 = e;
        int s1 = atomicAdd(&counts[e1], 1);
        list[e1 * T_TOKENS + s1] = t;  wtmp[e1 * T_TOKENS + s1] = p[e1];
        int s2 = atomicAdd(&counts[e2], 1);
        list[e2 * T_TOKENS + s2] = t;  wtmp[e2 * T_TOKENS + s2] = p[e2];
    }
}

// ---------------------------------------------------------------- finalize
// pad each expert list to multiple of BM with (token=0, w=0); prefix offsets
__global__ void k_finalize(const int* __restrict__ counts, int* __restrict__ pcount,
                           int* __restrict__ offs, int* __restrict__ list,
                           float* __restrict__ wtmp) {
    __shared__ int sp[E_NUM];
    if (threadIdx.x == 0) {
        int acc = 0;
        for (int e = 0; e < E_NUM; ++e) {
            int pc = (counts[e] + BM - 1) / BM * BM;
            sp[e] = pc;
            pcount[e] = pc;
            offs[e] = acc;
            acc += pc;
        }
    }
    __syncthreads();
    for (int e = 0; e < E_NUM; ++e) {
        int c = counts[e], pc = sp[e];
        for (int s = c + threadIdx.x; s < pc; s += 256) {
            list[e * T_TOKENS + s] = 0;
            wtmp[e * T_TOKENS + s] = 0.f;
        }
    }
}

// ---------------------------------------------------------------- x -> bf16
__global__ void k_cvt_x(const float* __restrict__ x, ushort_t* __restrict__ xb) {
    int n4 = T_TOKENS * D_DIM / 4;
    for (int j = blockIdx.x * 256 + threadIdx.x; j < n4; j += gridDim.x * 256) {
        float4v v = ((const float4v*)x)[j];
        unsigned long long o =
            (unsigned long long)f2bf(v[0]) |
            ((unsigned long long)f2bf(v[1]) << 16) |
            ((unsigned long long)f2bf(v[2]) << 32) |
            ((unsigned long long)f2bf(v[3]) << 48);
        ((unsigned long long*)xb)[j] = o;
    }
}

// ------------------------------------------------- weight transpose+convert
// in: [E][R][C] fp32 row-major -> out: [E][C][R] bf16 row-major
__global__ void k_transpose_cvt(const float* __restrict__ in, ushort_t* __restrict__ outp,
                                int R, int C) {
    __shared__ ushort_t tile[64][72];
    int e = blockIdx.z;
    int r0 = blockIdx.y * 64, c0 = blockIdx.x * 64;
    const float* ip = in + (size_t)e * R * C;
    ushort_t* op = outp + (size_t)e * R * C;
    int tr = threadIdx.x >> 6;          // 0..3
    int tc = threadIdx.x & 63;          // 0..63
#pragma unroll
    for (int i = 0; i < 16; ++i) {
        int r = tr + i * 4;
        tile[r][tc] = f2bf(ip[(size_t)(r0 + r) * C + c0 + tc]);
    }
    __syncthreads();
#pragma unroll
    for (int i = 0; i < 16; ++i) {
        int rr = tr + i * 4;            // output row = original col c0+rr
        op[(size_t)(c0 + rr) * R + r0 + tc] = tile[tc][rr];
    }
}

// ---------------------------------------------------------------- up GEMM
// C[m_local, n] = gelu( sum_k xb[token[m_local],k] * wupT[e][n,k] + b_up[e,n] )
// stored bf16 into h[(offs[e]+mb*BM+m_local), n]
__global__ void k_up_gemm(const ushort_t* __restrict__ xb, const ushort_t* __restrict__ wupT,
                          const float* __restrict__ b_up, const int* __restrict__ pcount,
                          const int* __restrict__ offs, const int* __restrict__ list,
                          ushort_t* __restrict__ h) {
    int e = blockIdx.z, mb = blockIdx.y, nb = blockIdx.x;
    if (mb * BM >= pcount[e]) return;
    __shared__ __align__(16) ushort_t As[BM][BK];
    __shared__ __align__(16) ushort_t Bs[BN][BK];
    int t = threadIdx.x, wave = t >> 6, lane = t & 63;
    int wm = wave >> 1, wn = wave & 1;

    const int lbase = e * T_TOKENS + mb * BM;
    int tokA0 = list[lbase + (t >> 2)];          // rows 0..63
    int tokA1 = list[lbase + 64 + (t >> 2)];     // rows 64..127
    const ushort_t* wb = wupT + (size_t)e * F_DIM * D_DIM + (size_t)(nb * BN) * D_DIM;

    float4v acc[4][4];
#pragma unroll
    for (int i = 0; i < 4; ++i)
#pragma unroll
        for (int j = 0; j < 4; ++j)
#pragma unroll
            for (int q = 0; q < 4; ++q) acc[i][j][q] = 0.f;

    char* AsB = (char*)&As[0][0];
    char* BsB = (char*)&Bs[0][0];
    int koff = (t & 3) * 8;                       // element offset within row (16B chunk)

    for (int kt = 0; kt < D_DIM / BK; ++kt) {
        int k0 = kt * BK;
        // stage A (gathered rows) and B, 2 chunks each per thread
        GLOAD_LDS16(xb + (size_t)tokA0 * D_DIM + k0 + koff, AsB + wave * 1024);
        GLOAD_LDS16(xb + (size_t)tokA1 * D_DIM + k0 + koff, AsB + 4096 + wave * 1024);
        GLOAD_LDS16(wb + (size_t)(t >> 2) * D_DIM + k0 + koff, BsB + wave * 1024);
        GLOAD_LDS16(wb + (size_t)(64 + (t >> 2)) * D_DIM + k0 + koff, BsB + 4096 + wave * 1024);
        __syncthreads();

        short8 af[4], bfr[4];
#pragma unroll
        for (int m = 0; m < 4; ++m)
            af[m] = *(const short8*)&As[wm * 64 + m * 16 + (lane & 15)][(lane >> 4) * 8];
#pragma unroll
        for (int n = 0; n < 4; ++n)
            bfr[n] = *(const short8*)&Bs[wn * 64 + n * 16 + (lane & 15)][(lane >> 4) * 8];
#pragma unroll
        for (int m = 0; m < 4; ++m)
#pragma unroll
            for (int n = 0; n < 4; ++n)
                acc[m][n] = __builtin_amdgcn_mfma_f32_16x16x32_bf16(af[m], bfr[n], acc[m][n], 0, 0, 0);
        __syncthreads();
    }

    int gbase = offs[e] + mb * BM;
#pragma unroll
    for (int m = 0; m < 4; ++m) {
        int row_local = wm * 64 + m * 16 + (lane >> 4) * 4;
#pragma unroll
        for (int n = 0; n < 4; ++n) {
            int col = nb * BN + wn * 64 + n * 16 + (lane & 15);
            float bia = b_up[e * F_DIM + col];
#pragma unroll
            for (int j = 0; j < 4; ++j) {
                float v = acc[m][n][j] + bia;
                float g = 0.5f * v * (1.f + erff(v * 0.70710678118f));   // exact gelu
                h[(size_t)(gbase + row_local + j) * F_DIM + col] = f2bf(g);
            }
        }
    }
}

// ---------------------------------------------------------------- down GEMM + combine
// y = h @ w_down^T + b_down ; out[token] += w * y  (atomic, 2 adds/elem)
__global__ void k_down_gemm(const ushort_t* __restrict__ h, const ushort_t* __restrict__ wdT,
                            const float* __restrict__ b_down, const int* __restrict__ pcount,
                            const int* __restrict__ offs, const int* __restrict__ list,
                            const float* __restrict__ wtmp, float* __restrict__ out) {
    int e = blockIdx.z, mb = blockIdx.y, nb = blockIdx.x;
    if (mb * BM >= pcount[e]) return;
    __shared__ __align__(16) ushort_t As[BM][BK];
    __shared__ __align__(16) ushort_t Bs[BN][BK];
    int t = threadIdx.x, wave = t >> 6, lane = t & 63;
    int wm = wave >> 1, wn = wave & 1;

    const ushort_t* ha = h + (size_t)(offs[e] + mb * BM) * F_DIM;
    const ushort_t* wb = wdT + (size_t)e * D_DIM * F_DIM + (size_t)(nb * BN) * F_DIM;

    float4v acc[4][4];
#pragma unroll
    for (int i = 0; i < 4; ++i)
#pragma unroll
        for (int j = 0; j < 4; ++j)
#pragma unroll
            for (int q = 0; q < 4; ++q) acc[i][j][q] = 0.f;

    char* AsB = (char*)&As[0][0];
    char* BsB = (char*)&Bs[0][0];
    int koff = (t & 3) * 8;

    for (int kt = 0; kt < F_DIM / BK; ++kt) {
        int k0 = kt * BK;
        GLOAD_LDS16(ha + (size_t)(t >> 2) * F_DIM + k0 + koff, AsB + wave * 1024);
        GLOAD_LDS16(ha + (size_t)(64 + (t >> 2)) * F_DIM + k0 + koff, AsB + 4096 + wave * 1024);
        GLOAD_LDS16(wb + (size_t)(t >> 2) * F_DIM + k0 + koff, BsB + wave * 1024);
        GLOAD_LDS16(wb + (size_t)(64 + (t >> 2)) * F_DIM + k0 + koff, BsB + 4096 + wave * 1024);
        __syncthreads();

        short8 af[4], bfr[4];
#pragma unroll
        for (int m = 0; m < 4; ++m)
            af[m] = *(const short8*)&As[wm * 64 + m * 16 + (lane & 15)][(lane >> 4) * 8];
#pragma unroll
        for (int n = 0; n < 4; ++n)
            bfr[n] = *(const short8*)&Bs[wn * 64 + n * 16 + (lane & 15)][(lane >> 4) * 8];
#pragma unroll
        for (int m = 0; m < 4; ++m)
#pragma unroll
            for (int n = 0; n < 4; ++n)
                acc[m][n] = __builtin_amdgcn_mfma_f32_16x16x32_bf16(af[m], bfr[n], acc[m][n], 0, 0, 0);
        __syncthreads();
    }

    int lb = e * T_TOKENS + mb * BM;
#pragma unroll
    for (int m = 0; m < 4; ++m) {
        int row_local = wm * 64 + m * 16 + (lane >> 4) * 4;
#pragma unroll
        for (int j = 0; j < 4; ++j) {
            int rl = row_local + j;
            int tok = list[lb + rl];
            float w = wtmp[lb + rl];
            if (w != 0.f) {
#pragma unroll
                for (int n = 0; n < 4; ++n) {
                    int col = nb * BN + wn * 64 + n * 16 + (lane & 15);
                    float v = acc[m][n][j] + b_down[e * D_DIM + col];
                    atomicAdd(&out[(size_t)tok * D_DIM + col], w * v);
                }
            }
        }
    }
}

// ---------------------------------------------------------------- launch
extern "C" void kernel_launch(void* const* d_in, const int* in_sizes, int n_in,
                              void* d_out, int out_size, void* d_ws, size_t ws_size,
                              hipStream_t stream) {
    const float* x   = (const float*)d_in[0];   // [2,2048,768]
    const float* gw  = (const float*)d_in[1];   // [768,8]
    const float* wup = (const float*)d_in[2];   // [8,768,3072]
    const float* bup = (const float*)d_in[3];   // [8,3072]
    const float* wdn = (const float*)d_in[4];   // [8,3072,768]
    const float* bdn = (const float*)d_in[5];   // [8,768]
    float* out = (float*)d_out;

    char* ws = (char*)d_ws;
    int*   counts = (int*)(ws);
    int*   pcount = (int*)(ws + 32);
    int*   offs   = (int*)(ws + 64);
    int*   list   = (int*)(ws + 256);
    float* wtmp   = (float*)(ws + 256 + (size_t)E_NUM * T_TOKENS * 4);
    size_t p = 256 + (size_t)E_NUM * T_TOKENS * 8;
    p = (p + 255) & ~(size_t)255;
    ushort_t* xb   = (ushort_t*)(ws + p); p += (size_t)T_TOKENS * D_DIM * 2;
    ushort_t* wupT = (ushort_t*)(ws + p); p += (size_t)E_NUM * D_DIM * F_DIM * 2;
    ushort_t* wdnT = (ushort_t*)(ws + p); p += (size_t)E_NUM * D_DIM * F_DIM * 2;
    ushort_t* hbuf = (ushort_t*)(ws + p); p += (size_t)(2 * T_TOKENS + E_NUM * BM) * F_DIM * 2;
    // total ~139 MB of ws

    k_init<<<2048, 256, 0, stream>>>(out, counts);
    k_gate<<<T_TOKENS / 4, 256, 0, stream>>>(x, gw, counts, list, wtmp);
    k_finalize<<<1, 256, 0, stream>>>(counts, pcount, offs, list, wtmp);
    k_cvt_x<<<1024, 256, 0, stream>>>(x, xb);
    k_transpose_cvt<<<dim3(F_DIM / 64, D_DIM / 64, E_NUM), 256, 0, stream>>>(wup, wupT, D_DIM, F_DIM);
    k_transpose_cvt<<<dim3(D_DIM / 64, F_DIM / 64, E_NUM), 256, 0, stream>>>(wdn, wdnT, F_DIM, D_DIM);
    k_up_gemm<<<dim3(F_DIM / BN, T_TOKENS / BM, E_NUM), 256, 0, stream>>>(
        xb, wupT, bup, pcount, offs, list, hbuf);
    k_down_gemm<<<dim3(D_DIM / BN, T_TOKENS / BM, E_NUM), 256, 0, stream>>>(
        hbuf, wdnT, bdn, pcount, offs, list, wtmp, out);
}

// Round 2
// 340.309 us; speedup vs baseline: 1.1412x; 1.1412x over previous
//
#include <hip/hip_runtime.h>
#include <hip/hip_bf16.h>
#include <math.h>

// Problem constants (B=2,S=2048 -> T=4096 tokens)
#define T_TOKENS 4096
#define D_DIM 768
#define F_DIM 3072
#define E_NUM 8

#define BM 128
#define BN 128
#define BK 32
#define RBMAX 72          // max padded row-blocks: (8192 + 8*127)/128 <= 72
#define KSPLIT 2
#define KCH (F_DIM / KSPLIT)   // 1536 per down-GEMM K-chunk

typedef __attribute__((ext_vector_type(8))) short short8;
typedef __attribute__((ext_vector_type(4))) float float4v;
typedef unsigned short ushort_t;

__device__ __forceinline__ ushort_t f2bf(float f) {
    union { float f; unsigned u; } v; v.f = f;
    unsigned r = v.u + 0x7fffu + ((v.u >> 16) & 1u);   // RNE
    return (ushort_t)(r >> 16);
}

__device__ __forceinline__ float gelu_fast(float v) {
    // tanh-form gelu via sigmoid: 0.5v(1+tanh(u)) = v*sigmoid(2u)
    float u = v + 0.044715f * v * v * v;
    return v / (1.f + __expf(-1.5957691216f * u));
}

#define GLOAD_LDS16(gp, lp) __builtin_amdgcn_global_load_lds( \
    (const __attribute__((address_space(1))) void*)(gp),      \
    (__attribute__((address_space(3))) void*)(lp), 16, 0, 0)

// ---------------------------------------------------------------- init
__global__ void k_init(float* __restrict__ out, int* __restrict__ counts) {
    if (blockIdx.x == 0 && threadIdx.x < E_NUM) counts[threadIdx.x] = 0;
    int n4 = T_TOKENS * D_DIM / 4;
    float4v z = {0.f, 0.f, 0.f, 0.f};
    for (int j = blockIdx.x * 256 + threadIdx.x; j < n4; j += gridDim.x * 256)
        ((float4v*)out)[j] = z;
}

// ---------------------------------------------------------------- gate
__global__ void k_gate(const float* __restrict__ x, const float* __restrict__ gw,
                       int* __restrict__ counts, int* __restrict__ list,
                       float* __restrict__ wtmp) {
    int wave = threadIdx.x >> 6;
    int lane = threadIdx.x & 63;
    int t = blockIdx.x * 4 + wave;
    if (t >= T_TOKENS) return;
    float acc[E_NUM];
#pragma unroll
    for (int e = 0; e < E_NUM; ++e) acc[e] = 0.f;
    const float* xr = x + (size_t)t * D_DIM;
    for (int d = lane; d < D_DIM; d += 64) {
        float xv = xr[d];
        const float* g = gw + d * E_NUM;
#pragma unroll
        for (int e = 0; e < E_NUM; ++e) acc[e] += xv * g[e];
    }
#pragma unroll
    for (int e = 0; e < E_NUM; ++e) {
#pragma unroll
        for (int s = 32; s >= 1; s >>= 1) acc[e] += __shfl_xor(acc[e], s);
    }
    if (lane == 0) {
        float mx = acc[0];
#pragma unroll
        for (int e = 1; e < E_NUM; ++e) mx = fmaxf(mx, acc[e]);
        float p[E_NUM], sum = 0.f;
#pragma unroll
        for (int e = 0; e < E_NUM; ++e) { p[e] = expf(acc[e] - mx); sum += p[e]; }
        float inv = 1.f / sum;
#pragma unroll
        for (int e = 0; e < E_NUM; ++e) p[e] *= inv;
        int e1 = 0;
#pragma unroll
        for (int e = 1; e < E_NUM; ++e) if (p[e] > p[e1]) e1 = e;
        int e2 = (e1 == 0) ? 1 : 0;
#pragma unroll
        for (int e = 0; e < E_NUM; ++e) if (e != e1 && p[e] > p[e2]) e2 = e;
        int s1 = atomicAdd(&counts[e1], 1);
        list[e1 * T_TOKENS + s1] = t;  wtmp[e1 * T_TOKENS + s1] = p[e1];
        int s2 = atomicAdd(&counts[e2], 1);
        list[e2 * T_TOKENS + s2] = t;  wtmp[e2 * T_TOKENS + s2] = p[e2];
    }
}

// ---------------------------------------------------------------- finalize
// compute padded counts, global padded-row offsets, row-block -> expert map
__global__ void k_finalize(const int* __restrict__ counts, int* __restrict__ pcount,
                           int* __restrict__ offs, int* __restrict__ nrb,
                           int* __restrict__ rbmap) {
    if (threadIdx.x == 0) {
        int acc = 0, rb = 0;
        for (int e = 0; e < E_NUM; ++e) {
            int pc = (counts[e] + BM - 1) / BM * BM;
            pcount[e] = pc;
            offs[e] = acc;
            for (int i = 0; i < pc / BM; ++i) rbmap[rb++] = e;
            acc += pc;
        }
        nrb[0] = rb;
    }
}

// ---------------------------------------------------------------- compact
// per-expert lists -> global padded-row clist/cw (pad: token 0, weight 0)
__global__ void k_compact(const int* __restrict__ counts, const int* __restrict__ pcount,
                          const int* __restrict__ offs, const int* __restrict__ list,
                          const float* __restrict__ wtmp, int* __restrict__ clist,
                          float* __restrict__ cw) {
    int e = blockIdx.y;
    int s = blockIdx.x * 256 + threadIdx.x;
    if (s >= pcount[e]) return;
    int g = offs[e] + s;
    if (s < counts[e]) {
        clist[g] = list[e * T_TOKENS + s];
        cw[g] = wtmp[e * T_TOKENS + s];
    } else {
        clist[g] = 0;
        cw[g] = 0.f;
    }
}

// ---------------------------------------------------------------- x -> bf16
__global__ void k_cvt_x(const float* __restrict__ x, ushort_t* __restrict__ xb) {
    int n4 = T_TOKENS * D_DIM / 4;
    for (int j = blockIdx.x * 256 + threadIdx.x; j < n4; j += gridDim.x * 256) {
        float4v v = ((const float4v*)x)[j];
        unsigned long long o =
            (unsigned long long)f2bf(v[0]) |
            ((unsigned long long)f2bf(v[1]) << 16) |
            ((unsigned long long)f2bf(v[2]) << 32) |
            ((unsigned long long)f2bf(v[3]) << 48);
        ((unsigned long long*)xb)[j] = o;
    }
}

// ------------------------------------------------- weight transpose+convert
// in: [E][R][C] fp32 row-major -> out: [E][C][R] bf16 row-major
__global__ void k_transpose_cvt(const float* __restrict__ in, ushort_t* __restrict__ outp,
                                int R, int C) {
    __shared__ float tile[64][65];
    int e = blockIdx.z;
    int r0 = blockIdx.y * 64, c0 = blockIdx.x * 64;
    const float* ip = in + (size_t)e * R * C;
    ushort_t* op = outp + (size_t)e * R * C;
    int tr = threadIdx.x >> 6;          // 0..3
    int tc = threadIdx.x & 63;          // 0..63
#pragma unroll
    for (int i = 0; i < 16; ++i) {
        int r = tr + i * 4;
        tile[r][tc] = ip[(size_t)(r0 + r) * C + c0 + tc];
    }
    __syncthreads();
#pragma unroll
    for (int i = 0; i < 16; ++i) {
        int rr = tr + i * 4;            // output row = original col c0+rr
        op[(size_t)(c0 + rr) * R + r0 + tc] = f2bf(tile[tc][rr]);
    }
}

// ---------------------------------------------------------------- up GEMM
// hbuf[grow, n] = gelu( sum_k xb[clist[grow],k] * wupT[e][n,k] + b_up[e,n] )
__global__ void k_up_gemm(const ushort_t* __restrict__ xb, const ushort_t* __restrict__ wupT,
                          const float* __restrict__ b_up, const int* __restrict__ nrb,
                          const int* __restrict__ rbmap, const int* __restrict__ clist,
                          ushort_t* __restrict__ h) {
    int rb = blockIdx.y;
    if (rb >= nrb[0]) return;
    int e = rbmap[rb], nb = blockIdx.x;
    __shared__ __align__(16) ushort_t As[BM][BK];
    __shared__ __align__(16) ushort_t Bs[BN][BK];
    int t = threadIdx.x, wave = t >> 6, lane = t & 63;
    int wm = wave >> 1, wn = wave & 1;

    int row0 = rb * BM;
    int tokA0 = clist[row0 + (t >> 2)];
    int tokA1 = clist[row0 + 64 + (t >> 2)];
    const ushort_t* wb = wupT + (size_t)e * F_DIM * D_DIM + (size_t)(nb * BN) * D_DIM;

    float4v acc[4][4];
#pragma unroll
    for (int i = 0; i < 4; ++i)
#pragma unroll
        for (int j = 0; j < 4; ++j)
#pragma unroll
            for (int q = 0; q < 4; ++q) acc[i][j][q] = 0.f;

    char* AsB = (char*)&As[0][0];
    char* BsB = (char*)&Bs[0][0];
    // LDS chunk swizzle: slot s of row r holds global chunk s ^ ((r>>1)&3).
    // Staged source chunk for this thread (rows t>>2 and t>>2+64 share p):
    int csw = (((t & 3) ^ ((t >> 3) & 3))) * 8;    // element offset in row
    // read-side swizzled chunk offset (row parity pattern identical for all m/n):
    int swoff = (((lane >> 4) ^ (((lane & 15) >> 1) & 3))) * 8;

    for (int kt = 0; kt < D_DIM / BK; ++kt) {
        int k0 = kt * BK;
        GLOAD_LDS16(xb + (size_t)tokA0 * D_DIM + k0 + csw, AsB + wave * 1024);
        GLOAD_LDS16(xb + (size_t)tokA1 * D_DIM + k0 + csw, AsB + 4096 + wave * 1024);
        GLOAD_LDS16(wb + (size_t)(t >> 2) * D_DIM + k0 + csw, BsB + wave * 1024);
        GLOAD_LDS16(wb + (size_t)(64 + (t >> 2)) * D_DIM + k0 + csw, BsB + 4096 + wave * 1024);
        __syncthreads();

        short8 af[4], bfr[4];
#pragma unroll
        for (int m = 0; m < 4; ++m)
            af[m] = *(const short8*)&As[wm * 64 + m * 16 + (lane & 15)][swoff];
#pragma unroll
        for (int n = 0; n < 4; ++n)
            bfr[n] = *(const short8*)&Bs[wn * 64 + n * 16 + (lane & 15)][swoff];
#pragma unroll
        for (int m = 0; m < 4; ++m)
#pragma unroll
            for (int n = 0; n < 4; ++n)
                acc[m][n] = __builtin_amdgcn_mfma_f32_16x16x32_bf16(af[m], bfr[n], acc[m][n], 0, 0, 0);
        __syncthreads();
    }

#pragma unroll
    for (int m = 0; m < 4; ++m) {
        int row_local = wm * 64 + m * 16 + (lane >> 4) * 4;
#pragma unroll
        for (int n = 0; n < 4; ++n) {
            int col = nb * BN + wn * 64 + n * 16 + (lane & 15);
            float bia = b_up[e * F_DIM + col];
#pragma unroll
            for (int j = 0; j < 4; ++j) {
                float v = acc[m][n][j] + bia;
                h[(size_t)(row0 + row_local + j) * F_DIM + col] = f2bf(gelu_fast(v));
            }
        }
    }
}

// ---------------------------------------------------------------- down GEMM + combine
// out[clist[grow]] += cw[grow] * (h[grow] @ w_down[e]^T + (kc==0)*b_down[e])
__global__ void k_down_gemm(const ushort_t* __restrict__ h, const ushort_t* __restrict__ wdT,
                            const float* __restrict__ b_down, const int* __restrict__ nrb,
                            const int* __restrict__ rbmap, const int* __restrict__ clist,
                            const float* __restrict__ cw, float* __restrict__ out) {
    int rb = blockIdx.y;
    if (rb >= nrb[0]) return;
    int e = rbmap[rb], nb = blockIdx.x, kc = blockIdx.z;
    __shared__ __align__(16) ushort_t As[BM][BK];
    __shared__ __align__(16) ushort_t Bs[BN][BK];
    int t = threadIdx.x, wave = t >> 6, lane = t & 63;
    int wm = wave >> 1, wn = wave & 1;

    int row0 = rb * BM;
    int kbase = kc * KCH;
    const ushort_t* ha = h + (size_t)row0 * F_DIM + kbase;
    const ushort_t* wb = wdT + (size_t)e * D_DIM * F_DIM + (size_t)(nb * BN) * F_DIM + kbase;

    float4v acc[4][4];
#pragma unroll
    for (int i = 0; i < 4; ++i)
#pragma unroll
        for (int j = 0; j < 4; ++j)
#pragma unroll
            for (int q = 0; q < 4; ++q) acc[i][j][q] = 0.f;

    char* AsB = (char*)&As[0][0];
    char* BsB = (char*)&Bs[0][0];
    int csw = (((t & 3) ^ ((t >> 3) & 3))) * 8;
    int swoff = (((lane >> 4) ^ (((lane & 15) >> 1) & 3))) * 8;

    for (int kt = 0; kt < KCH / BK; ++kt) {
        int k0 = kt * BK;
        GLOAD_LDS16(ha + (size_t)(t >> 2) * F_DIM + k0 + csw, AsB + wave * 1024);
        GLOAD_LDS16(ha + (size_t)(64 + (t >> 2)) * F_DIM + k0 + csw, AsB + 4096 + wave * 1024);
        GLOAD_LDS16(wb + (size_t)(t >> 2) * F_DIM + k0 + csw, BsB + wave * 1024);
        GLOAD_LDS16(wb + (size_t)(64 + (t >> 2)) * F_DIM + k0 + csw, BsB + 4096 + wave * 1024);
        __syncthreads();

        short8 af[4], bfr[4];
#pragma unroll
        for (int m = 0; m < 4; ++m)
            af[m] = *(const short8*)&As[wm * 64 + m * 16 + (lane & 15)][swoff];
#pragma unroll
        for (int n = 0; n < 4; ++n)
            bfr[n] = *(const short8*)&Bs[wn * 64 + n * 16 + (lane & 15)][swoff];
#pragma unroll
        for (int m = 0; m < 4; ++m)
#pragma unroll
            for (int n = 0; n < 4; ++n)
                acc[m][n] = __builtin_amdgcn_mfma_f32_16x16x32_bf16(af[m], bfr[n], acc[m][n], 0, 0, 0);
        __syncthreads();
    }

#pragma unroll
    for (int m = 0; m < 4; ++m) {
        int row_local = wm * 64 + m * 16 + (lane >> 4) * 4;
#pragma unroll
        for (int j = 0; j < 4; ++j) {
            int rl = row0 + row_local + j;
            int tok = clist[rl];
            float w = cw[rl];
            if (w != 0.f) {
#pragma unroll
                for (int n = 0; n < 4; ++n) {
                    int col = nb * BN + wn * 64 + n * 16 + (lane & 15);
                    float v = acc[m][n][j];
                    if (kc == 0) v += b_down[e * D_DIM + col];
                    atomicAdd(&out[(size_t)tok * D_DIM + col], w * v);
                }
            }
        }
    }
}

// ---------------------------------------------------------------- launch
extern "C" void kernel_launch(void* const* d_in, const int* in_sizes, int n_in,
                              void* d_out, int out_size, void* d_ws, size_t ws_size,
                              hipStream_t stream) {
    const float* x   = (const float*)d_in[0];   // [2,2048,768]
    const float* gw  = (const float*)d_in[1];   // [768,8]
    const float* wup = (const float*)d_in[2];   // [8,768,3072]
    const float* bup = (const float*)d_in[3];   // [8,3072]
    const float* wdn = (const float*)d_in[4];   // [8,3072,768]
    const float* bdn = (const float*)d_in[5];   // [8,768]
    float* out = (float*)d_out;

    char* ws = (char*)d_ws;
    int*   counts = (int*)(ws);
    int*   pcount = (int*)(ws + 32);
    int*   offs   = (int*)(ws + 64);
    int*   nrb    = (int*)(ws + 96);
    int*   rbmap  = (int*)(ws + 128);          // 128 ints
    int*   list   = (int*)(ws + 1024);
    float* wtmp   = (float*)(ws + 1024 + (size_t)E_NUM * T_TOKENS * 4);
    size_t p = 1024 + (size_t)E_NUM * T_TOKENS * 8;
    int*   clist  = (int*)(ws + p); p += (size_t)(RBMAX * BM) * 4;
    float* cwp    = (float*)(ws + p); p += (size_t)(RBMAX * BM) * 4;
    p = (p + 255) & ~(size_t)255;
    ushort_t* xb   = (ushort_t*)(ws + p); p += (size_t)T_TOKENS * D_DIM * 2;
    ushort_t* wupT = (ushort_t*)(ws + p); p += (size_t)E_NUM * D_DIM * F_DIM * 2;
    ushort_t* wdnT = (ushort_t*)(ws + p); p += (size_t)E_NUM * D_DIM * F_DIM * 2;
    ushort_t* hbuf = (ushort_t*)(ws + p); p += (size_t)(RBMAX * BM) * F_DIM * 2;

    k_init<<<1024, 256, 0, stream>>>(out, counts);
    k_gate<<<T_TOKENS / 4, 256, 0, stream>>>(x, gw, counts, list, wtmp);
    k_finalize<<<1, 64, 0, stream>>>(counts, pcount, offs, nrb, rbmap);
    k_compact<<<dim3(T_TOKENS / 256, E_NUM), 256, 0, stream>>>(
        counts, pcount, offs, list, wtmp, clist, cwp);
    k_cvt_x<<<1024, 256, 0, stream>>>(x, xb);
    k_transpose_cvt<<<dim3(F_DIM / 64, D_DIM / 64, E_NUM), 256, 0, stream>>>(wup, wupT, D_DIM, F_DIM);
    k_transpose_cvt<<<dim3(D_DIM / 64, F_DIM / 64, E_NUM), 256, 0, stream>>>(wdn, wdnT, F_DIM, D_DIM);
    k_up_gemm<<<dim3(F_DIM / BN, RBMAX), 256, 0, stream>>>(
        xb, wupT, bup, nrb, rbmap, clist, hbuf);
    k_down_gemm<<<dim3(D_DIM / BN, RBMAX, KSPLIT), 256, 0, stream>>>(
        hbuf, wdnT, bdn, nrb, rbmap, clist, cwp, out);
}